// Round 8
// baseline (397.563 us; speedup 1.0000x reference)
//
#include <hip/hip_runtime.h>

#define BB 16
#define TT 8192
#define NN 128                     // N_PRE == N_POST
constexpr int CHUNK = 256;         // time-steps per block (2 K=128 sub-passes)
constexpr int NBLK  = BB * TT / CHUNK;   // 512 blocks
constexpr int OUTN  = NN * NN;           // 16384
constexpr int GS2   = 136;         // g row stride in halves (272 B, 16B-aligned)
constexpr int SLOTS = OUTN / 2;    // 8192 packed u32 slots per k-slice
constexpr int PROWS = 315;         // staged post rows: (t0, t0+315]

typedef _Float16 f16x8 __attribute__((ext_vector_type(8)));
typedef _Float16 f16x2 __attribute__((ext_vector_type(2)));
typedef float    f32x4 __attribute__((ext_vector_type(4)));

__device__ __forceinline__ unsigned short h16(float x) {
    _Float16 h = (_Float16)x;
    return __builtin_bit_cast(unsigned short, h);
}
__device__ __forceinline__ unsigned int pack2(float x, float y) {
    return (unsigned int)h16(x) | ((unsigned int)h16(y) << 16);
}

// grid 512 x 256 threads (4 waves). Block = one 256-step chunk of one batch.
// Phase 0: post tile as BITMASK in LDS: bits[m][c] bit j <=> spike at row m, q=4j+c.
//          (5 KB vs 80 KB -> 4 blocks/CU.)
// Per sub-pass s (K=128): wave wv filters window s*4+wv (32 steps, 2 q/lane)
// from the bitmask, dumps f16 g into a reused 34.8 KB buffer, MFMAs K=128.
template<bool ATOMIC>
__global__ __launch_bounds__(256, 4)
void stdp_main(const float* __restrict__ pre, const float* __restrict__ post,
               const int* __restrict__ dtp,
               unsigned int* __restrict__ part, float* __restrict__ wpost,
               float* __restrict__ outat)
{
    __shared__ __align__(16) unsigned int   bits_s[PROWS * 4];  // 5040 B
    __shared__ __align__(16) unsigned short g_s[NN * GS2];      // 34816 B

    const int tid   = threadIdx.x;
    const int blk   = blockIdx.x;
    const int b     = blk >> 5;          // 16 batches
    const int chunk = blk & 31;          // 32 chunks per batch
    const int t0    = chunk * CHUNK;
    const int wv    = tid >> 6;          // wave 0..3
    const int lane  = tid & 63;

    const float dtf = (float)(*dtp);
    const float r   = expf(-dtf * (1.0f / 20.0f));

    const float* pb = post + (size_t)b * TT * NN;
    const float* ab = pre  + (size_t)b * TT * NN;

    // ---------- phase 0: stage post bitmask (ballot packing) ----------
    for (int it = 0; it < 40; ++it) {
        const int half = lane >> 5;                  // 0: row A, 1: row B
        const int m    = it * 8 + wv * 2 + half;
        const int t    = t0 + 1 + m;
        const int c4   = (lane & 31) * 4;
        float4 v = make_float4(0.f, 0.f, 0.f, 0.f);
        if (m < PROWS && t < TT) v = *(const float4*)(pb + (size_t)t * NN + c4);
        const unsigned long long bx = __ballot(v.x != 0.0f);
        const unsigned long long by = __ballot(v.y != 0.0f);
        const unsigned long long bz = __ballot(v.z != 0.0f);
        const unsigned long long bw = __ballot(v.w != 0.0f);
        if (m < PROWS && (lane & 31) == 0) {         // lane 0 -> row A (lo), lane 32 -> row B (hi)
            const int sh = half * 32;
            *(uint4*)&bits_s[m * 4] = make_uint4(
                (unsigned int)(bx >> sh), (unsigned int)(by >> sh),
                (unsigned int)(bz >> sh), (unsigned int)(bw >> sh));
        }
    }
    __syncthreads();

    // lane's two q columns and their bit coordinates
    const int q0 = lane * 2;             // even q
    const int q1 = q0 + 1;
    const int c0 = q0 & 3;               // 0 or 2
    const int jb = q0 >> 2;              // same bit index for q0 and q1
    float ps0 = 0.f, ps1 = 0.f;          // spike sums (exact ints in f32)

    f32x4 acc[2][8];
    #pragma unroll
    for (int i = 0; i < 2; ++i)
        #pragma unroll
        for (int qt = 0; qt < 8; ++qt) acc[i][qt] = (f32x4){0.f, 0.f, 0.f, 0.f};

    const int pr0 = wv * 32;             // MFMA p-strip base

    #pragma unroll 1
    for (int s = 0; s < 2; ++s) {
        // ---------- filter window widx = s*4 + wv (32 steps, 2 q) ----------
        const int mb = (s * 4 + wv) * 32;           // P[ts+k] -> row mb+k-1
        unsigned int pk0[16], pk1[16];
        {
            // row read: one broadcast uint4, select 2 words, extract bit jb
            #define RDP(mrow, px, py) {                                   \
                const uint4 w4 = *(const uint4*)&bits_s[(mrow) * 4];      \
                const unsigned int w0 = (c0 & 2) ? w4.z : w4.x;           \
                const unsigned int w1 = (c0 & 2) ? w4.w : w4.y;           \
                px = (float)((w0 >> jb) & 1u);                            \
                py = (float)((w1 >> jb) & 1u);                            \
            }
            float px, py;
            RDP(mb + 31, px, py);                    // tau=1: P[ts+32]
            float wt = r;
            float gx = r * px, gy = r * py;
            ps0 += px; ps1 += py;
            #pragma unroll
            for (int tau = 2; tau <= 59; ++tau) {
                wt *= r;
                RDP(mb + 30 + tau, px, py);
                gx = fmaf(wt, px, gx);
                gy = fmaf(wt, py, gy);
            }
            const float r60 = wt * r;                // r^60, consistent weights
            pk0[15] = (unsigned int)h16(gx) << 16;
            pk1[15] = (unsigned int)h16(gy) << 16;
            // g[t] = r*(g[t+1]+P(t+1)) - r^60*P(t+60)
            #pragma unroll
            for (int c = 30; c >= 0; --c) {
                float p1x, p1y, p60x, p60y;
                RDP(mb + c,      p1x,  p1y);
                RDP(mb + c + 59, p60x, p60y);
                gx = r * (gx + p1x) - r60 * p60x;
                gy = r * (gy + p1y) - r60 * p60y;
                ps0 += p1x; ps1 += p1y;
                if (c & 1) {
                    pk0[c >> 1] = (unsigned int)h16(gx) << 16;
                    pk1[c >> 1] = (unsigned int)h16(gy) << 16;
                } else {
                    pk0[c >> 1] |= h16(gx);
                    pk1[c >> 1] |= h16(gy);
                }
            }
            #undef RDP
        }
        if (s == 1) __syncthreads();     // all MFMA reads of g(sub0) done before overwrite
        {
            unsigned short* d0 = &g_s[q0 * GS2 + wv * 32];
            unsigned short* d1 = &g_s[q1 * GS2 + wv * 32];
            #pragma unroll
            for (int k = 0; k < 4; ++k) {
                *(uint4*)(d0 + 8 * k) = make_uint4(pk0[4*k], pk0[4*k+1], pk0[4*k+2], pk0[4*k+3]);
                *(uint4*)(d1 + 8 * k) = make_uint4(pk1[4*k], pk1[4*k+1], pk1[4*k+2], pk1[4*k+3]);
            }
        }
        __syncthreads();                 // g(sub s) visible

        // ---------- MFMA: S += pre_sub^T @ g_sub, K=128, strip 32p x 128q ----------
        #pragma unroll
        for (int ks = 0; ks < 4; ++ks) {
            const int trow = t0 + s * 128 + ks * 32 + (lane >> 4) * 8;
            f16x8 af[2];
            #pragma unroll
            for (int i = 0; i < 2; ++i) {
                const float* src = ab + (size_t)trow * NN + pr0 + i * 16 + (lane & 15);
                #pragma unroll
                for (int j = 0; j < 8; ++j)
                    af[i][j] = (_Float16)src[(size_t)j * NN];   // 0/1 exact
            }
            const int koff = ks * 32 + (lane >> 4) * 8;
            #pragma unroll
            for (int qt = 0; qt < 8; ++qt) {
                const f16x8 bf = *(const f16x8*)&g_s[(qt * 16 + (lane & 15)) * GS2 + koff];
                acc[0][qt] = __builtin_amdgcn_mfma_f32_16x16x32_f16(af[0], bf, acc[0][qt], 0, 0, 0);
                acc[1][qt] = __builtin_amdgcn_mfma_f32_16x16x32_f16(af[1], bf, acc[1][qt], 0, 0, 0);
            }
        }
    }

    // ---------- spike column sums -> global atomics (exact integer adds) ----------
    atomicAdd(&wpost[q0], ps0);
    atomicAdd(&wpost[q1], ps1);
    if (chunk == 0 && tid < NN) atomicAdd(&wpost[tid], pb[tid]);  // missing t=0 row

    // ---------- write partial S: u32-packed f16 pairs, 256B/instr coalesced ----------
    if constexpr (!ATOMIC) {
        unsigned int* dst = part + (size_t)blk * SLOTS + wv * 2048 + lane;
        #pragma unroll
        for (int i = 0; i < 2; ++i)
            #pragma unroll
            for (int qt = 0; qt < 8; ++qt)
                #pragma unroll
                for (int rp = 0; rp < 2; ++rp)
                    dst[i * 1024 + qt * 128 + rp * 64] =
                        pack2(acc[i][qt][2 * rp], acc[i][qt][2 * rp + 1]);
    } else {
        #pragma unroll
        for (int i = 0; i < 2; ++i)
            #pragma unroll
            for (int qt = 0; qt < 8; ++qt)
                #pragma unroll
                for (int rg = 0; rg < 4; ++rg) {
                    const int prow = pr0 + i * 16 + (lane >> 4) * 4 + rg;
                    const int qcol = qt * 16 + (lane & 15);
                    atomicAdd(&outat[prow * NN + qcol], acc[i][qt][rg]);
                }
    }
}

// fused split-K reduce + hfac + epilogue: 128 blocks x 512 thr.
__global__ __launch_bounds__(512)
void finalize_ws(const unsigned int* __restrict__ part, const float* __restrict__ wpost,
                 const int* __restrict__ dtp, const float* __restrict__ W,
                 float* __restrict__ out)
{
    __shared__ float2 red[512];
    const int s    = threadIdx.x & 63;        // slot within block's 64
    const int kq   = threadIdx.x >> 6;        // 0..7
    const int slot = blockIdx.x * 64 + s;     // 0..8191
    float sx = 0.f, sy = 0.f;
    #pragma unroll 8
    for (int k = kq * 64; k < kq * 64 + 64; ++k) {
        const unsigned int v = part[(size_t)k * SLOTS + slot];
        const f16x2 h = __builtin_bit_cast(f16x2, v);
        sx += (float)h[0];
        sy += (float)h[1];
    }
    red[threadIdx.x] = make_float2(sx, sy);
    __syncthreads();
    if (threadIdx.x < 64) {
        float tx = red[s].x, ty = red[s].y;
        #pragma unroll
        for (int g = 1; g < 8; ++g) {
            const float2 v = red[g * 64 + s];
            tx += v.x; ty += v.y;
        }
        // un-permute slot -> (p, q) for the 4-wave / 32p-strip layout
        const int lane = slot & 63;
        const int rp   = (slot >> 6) & 1;
        const int qt   = (slot >> 7) & 7;
        const int ii   = (slot >> 10) & 1;
        const int wv   = slot >> 11;
        const int p    = wv * 32 + ii * 16 + ((lane >> 4) << 2) + rp * 2;
        const int q    = qt * 16 + (lane & 15);
        const float scale = (float)((0.005 - 0.00525) / (double)(BB * TT));
        const float dtf   = (float)(*dtp);
        const float alpha = dtf * 1e-3f;
        const float hf    = -0.001f * (alpha * (wpost[q] * (1.0f / (BB * TT)) - 0.1f));
        out[p * NN + q]       = fmaf(tx, scale, hf * W[p * NN + q]);
        out[(p + 1) * NN + q] = fmaf(ty, scale, hf * W[(p + 1) * NN + q]);
    }
}

// fallback epilogue when S was atomically accumulated in d_out
__global__ void finalize_at(const float* __restrict__ wpost, const int* __restrict__ dtp,
                            const float* __restrict__ W, float* __restrict__ out)
{
    const int i = (blockIdx.x * 256 + threadIdx.x) * 2;
    const int q = i & 127;
    const float scale = (float)((0.005 - 0.00525) / (double)(BB * TT));
    const float dtf   = (float)(*dtp);
    const float alpha = dtf * 1e-3f;
    const float hf0   = -0.001f * (alpha * (wpost[q]     * (1.0f / (BB * TT)) - 0.1f));
    const float hf1   = -0.001f * (alpha * (wpost[q + 1] * (1.0f / (BB * TT)) - 0.1f));
    float2 sv = *(const float2*)(out + i);
    float2 w  = *(const float2*)(W + i);
    float2 o;
    o.x = fmaf(sv.x, scale, hf0 * w.x);
    o.y = fmaf(sv.y, scale, hf1 * w.y);
    *(float2*)(out + i) = o;
}

extern "C" void kernel_launch(void* const* d_in, const int* in_sizes, int n_in,
                              void* d_out, int out_size, void* d_ws, size_t ws_size,
                              hipStream_t stream)
{
    const float* pre  = (const float*)d_in[0];
    const float* post = (const float*)d_in[1];
    const float* W    = (const float*)d_in[2];
    const int*   dtp  = (const int*)d_in[3];
    float* out = (float*)d_out;

    const size_t part_bytes = (size_t)NBLK * SLOTS * sizeof(unsigned int); // 16 MiB
    const size_t need = part_bytes + NN * sizeof(float);

    if (ws_size >= need) {
        unsigned int* part = (unsigned int*)d_ws;
        float* wpost       = (float*)((char*)d_ws + part_bytes);
        hipMemsetAsync(wpost, 0, NN * sizeof(float), stream);
        hipLaunchKernelGGL((stdp_main<false>), dim3(NBLK), dim3(256), 0, stream,
                           pre, post, dtp, part, wpost, (float*)nullptr);
        hipLaunchKernelGGL(finalize_ws, dim3(SLOTS / 64), dim3(512), 0, stream,
                           part, wpost, dtp, W, out);
    } else {
        // atomic fallback: needs only 512 B of workspace
        float* wpost = (float*)d_ws;
        hipMemsetAsync(d_out, 0, OUTN * sizeof(float), stream);
        hipMemsetAsync(wpost, 0, NN * sizeof(float), stream);
        hipLaunchKernelGGL((stdp_main<true>), dim3(NBLK), dim3(256), 0, stream,
                           pre, post, dtp, (unsigned int*)nullptr, wpost, out);
        hipLaunchKernelGGL(finalize_at, dim3(OUTN / 512), dim3(256), 0, stream,
                           wpost, dtp, W, out);
    }
}

// Round 9
// 170.882 us; speedup vs baseline: 2.3265x; 2.3265x over previous
//
#include <hip/hip_runtime.h>

#define BB 16
#define TT 8192
#define NN 128                     // N_PRE == N_POST
constexpr int CHUNK = 256;         // time-steps per chunk
constexpr int NCH   = BB * TT / CHUNK;   // 512 chunks
constexpr int NBLK  = NCH * 2;           // 1024 blocks (chunk x q-half)
constexpr int OUTN  = NN * NN;           // 16384
constexpr int QH    = 64;          // q columns per block
constexpr int GSQ   = 264;         // g row stride in halves (528 B, 16B-aligned)
constexpr int SLOTS = 8192;        // packed u32 slots per chunk-slice (2 qh x 4096)
constexpr int PROWS = 315;         // staged post rows: (t0, t0+315]

typedef _Float16 f16x8 __attribute__((ext_vector_type(8)));
typedef _Float16 f16x2 __attribute__((ext_vector_type(2)));
typedef float    f32x4 __attribute__((ext_vector_type(4)));

__device__ __forceinline__ unsigned short h16(float x) {
    _Float16 h = (_Float16)x;
    return __builtin_bit_cast(unsigned short, h);
}
__device__ __forceinline__ unsigned int pack2(float x, float y) {
    return (unsigned int)h16(x) | ((unsigned int)h16(y) << 16);
}
__device__ __forceinline__ float ldLq(const unsigned short* p_lds, int m, int q) {
    _Float16 h = __builtin_bit_cast(_Float16, p_lds[m * QH + q]);
    return (float)h;
}

// grid 1024 x 256 threads (4 waves). Block = one 256-step chunk x one 64-q half.
// LDS 40,320 B -> 4 blocks/CU (4 independent barrier domains; grid = 4*256 exactly).
// Phase 0: stage post rows (t0, t0+315] x 64 q as f16 (float4-coalesced).
// Phase 1: wave wv filters 64-step window wv (1 q per lane) into pk regs.
// Phase 2: g overwrites post tile; MFMA K=256, wave strip 32p x 64q (acc = 32 AGPR).
template<bool ATOMIC>
__global__ __launch_bounds__(256, 4)
void stdp_main(const float* __restrict__ pre, const float* __restrict__ post,
               const int* __restrict__ dtp,
               unsigned int* __restrict__ part, float* __restrict__ wpost,
               float* __restrict__ outat)
{
    __shared__ __align__(16) char smem[PROWS * QH * 2];      // 40,320 B
    unsigned short* post_lds = (unsigned short*)smem;        // [315][64] f16
    unsigned short* g_lds    = (unsigned short*)smem;        // [64][264] f16 (phase 2)
    float*          lds_ps   = (float*)(smem + QH * GSQ * 2);// [4][64] (phase 2, 33792+1024<=40320)

    const int tid    = threadIdx.x;
    const int blk    = blockIdx.x;
    const int chunkG = blk >> 1;         // 0..511
    const int qh     = blk & 1;          // q-half
    const int b      = chunkG >> 5;      // 16 batches
    const int chunk  = chunkG & 31;      // 32 chunks per batch
    const int t0     = chunk * CHUNK;
    const int wv     = tid >> 6;         // wave 0..3
    const int lane   = tid & 63;

    const float dtf = (float)(*dtp);
    const float r   = expf(-dtf * (1.0f / 20.0f));

    const float* pb = post + (size_t)b * TT * NN;
    const float* ab = pre  + (size_t)b * TT * NN;

    // ---------- phase 0: stage post tile (this block's 64 q) ----------
    {
        const int c  = tid & 15;         // float4 column within 64-q row
        const int mr = tid >> 4;         // starting row (0..15)
        for (int m = mr; m < PROWS; m += 16) {
            const int t = t0 + 1 + m;
            float4 v = make_float4(0.f, 0.f, 0.f, 0.f);
            if (t < TT) v = *(const float4*)(pb + (size_t)t * NN + qh * QH + c * 4);
            *(uint2*)&post_lds[m * QH + c * 4] =
                make_uint2(pack2(v.x, v.y), pack2(v.z, v.w));
        }
    }
    __syncthreads();

    // ---------- phase 1: filter 64-step window wv, one q per lane ----------
    const int base = wv * 64;            // P[ts+k] -> local row base+k-1
    float ps = 0.f;                      // post sum over (ts, ts+64]

    unsigned int pk[32];                 // 64 f16 steps
    {
        float p  = ldLq(post_lds, base + 63, lane);  // tau=1: P[ts+64]
        float wt = r;
        float g  = r * p;
        ps += p;
        #pragma unroll
        for (int tau = 2; tau <= 59; ++tau) {
            wt *= r;
            p = ldLq(post_lds, base + 62 + tau, lane);
            g = fmaf(wt, p, g);
        }
        const float r60 = wt * r;        // r^60, consistent with chained weights
        pk[31] = (unsigned int)h16(g) << 16;     // step 63 = high half of word 31
        // recurrence downward: g[t] = r*(g[t+1]+P(t+1)) - r^60*P(t+60)
        #pragma unroll
        for (int c = 62; c >= 0; --c) {
            const float p1  = ldLq(post_lds, base + c,      lane);  // P[ts+c+1]
            const float p60 = ldLq(post_lds, base + c + 59, lane);  // P[ts+c+60]
            g = r * (g + p1) - r60 * p60;
            ps += p1;
            if (c & 1) pk[c >> 1] = (unsigned int)h16(g) << 16;
            else       pk[c >> 1] |= h16(g);
        }
    }
    __syncthreads();                     // all post_lds reads done before overwrite

    // ---------- phase 2a: dump g over post region; stash ps ----------
    {
        unsigned short* d = &g_lds[lane * GSQ + wv * 64];   // 528B rows, 16B-aligned
        #pragma unroll
        for (int s = 0; s < 8; ++s)
            *(uint4*)(d + 8 * s) = make_uint4(pk[4*s], pk[4*s+1], pk[4*s+2], pk[4*s+3]);
        lds_ps[wv * QH + lane] = ps;
    }
    __syncthreads();

    // ---------- phase 2b: MFMA S[p,q] += pre^T @ g, K=256, strip 32p x 64q ----------
    const int pr0 = wv * 32;
    f32x4 acc[2][4];
    #pragma unroll
    for (int i = 0; i < 2; ++i)
        #pragma unroll
        for (int qt = 0; qt < 4; ++qt) acc[i][qt] = (f32x4){0.f, 0.f, 0.f, 0.f};

    #pragma unroll
    for (int ks = 0; ks < 8; ++ks) {
        const int trow = t0 + ks * 32 + (lane >> 4) * 8;    // A K-rows this lane covers
        f16x8 af[2];
        #pragma unroll
        for (int i = 0; i < 2; ++i) {
            const float* src = ab + (size_t)trow * NN + pr0 + i * 16 + (lane & 15);
            #pragma unroll
            for (int j = 0; j < 8; ++j)
                af[i][j] = (_Float16)src[(size_t)j * NN];   // 0/1 exact in fp16
        }
        const int koff = ks * 32 + (lane >> 4) * 8;
        #pragma unroll
        for (int qt = 0; qt < 4; ++qt) {
            const f16x8 bf = *(const f16x8*)&g_lds[(qt * 16 + (lane & 15)) * GSQ + koff];
            acc[0][qt] = __builtin_amdgcn_mfma_f32_16x16x32_f16(af[0], bf, acc[0][qt], 0, 0, 0);
            acc[1][qt] = __builtin_amdgcn_mfma_f32_16x16x32_f16(af[1], bf, acc[1][qt], 0, 0, 0);
        }
    }

    // ---------- write partial S: u32-packed f16 pairs, 256B/instr coalesced ----------
    if constexpr (!ATOMIC) {
        unsigned int* dst = part + (size_t)chunkG * SLOTS + qh * 4096 + wv * 1024 + lane;
        #pragma unroll
        for (int i = 0; i < 2; ++i)
            #pragma unroll
            for (int qt = 0; qt < 4; ++qt)
                #pragma unroll
                for (int rp = 0; rp < 2; ++rp)
                    dst[i * 512 + qt * 128 + rp * 64] =
                        pack2(acc[i][qt][2 * rp], acc[i][qt][2 * rp + 1]);
    } else {
        #pragma unroll
        for (int i = 0; i < 2; ++i)
            #pragma unroll
            for (int qt = 0; qt < 4; ++qt)
                #pragma unroll
                for (int rg = 0; rg < 4; ++rg) {
                    const int prow = pr0 + i * 16 + (lane >> 4) * 4 + rg;
                    const int qcol = qh * QH + qt * 16 + (lane & 15);
                    atomicAdd(&outat[prow * NN + qcol], acc[i][qt][rg]);
                }
    }

    // ---------- post column sums (lds_ps valid since pre-MFMA barrier) ----------
    if (tid < QH) {
        float s = lds_ps[tid] + lds_ps[QH + tid] + lds_ps[2 * QH + tid] + lds_ps[3 * QH + tid];
        const int q = qh * QH + tid;
        if (chunk == 0) s += pb[q];      // window (t0,t0+256] misses t=0 row once per batch
        if constexpr (ATOMIC) atomicAdd(&wpost[q], s);
        else wpost[(size_t)q * NCH + chunkG] = s;   // [q][512] for coalesced reduce
    }
}

// 128 blocks x 64 threads: block q reduces its NCH partial sums (coalesced), shfl tree.
__global__ void hfac_kernel(const float* __restrict__ wpost, const int* __restrict__ dtp,
                            float* __restrict__ hfac, int nb)
{
    const int q = blockIdx.x;
    float s = 0.f;
    for (int k = threadIdx.x; k < nb; k += 64) s += wpost[(size_t)q * nb + k];
    #pragma unroll
    for (int off = 32; off; off >>= 1) s += __shfl_down(s, off, 64);
    if (threadIdx.x == 0) {
        const float dtf   = (float)(*dtp);
        const float alpha = dtf * 1e-3f;
        const float mean  = s * (1.0f / (float)(BB * TT));
        hfac[q] = -0.001f * (alpha * (mean - 0.1f));
    }
}

// fused split-K reduce + epilogue: 128 blocks x 512 thr, 8-way k-split,
// 256B/instr coalesced part reads; un-permute + homeostatic epilogue.
__global__ __launch_bounds__(512)
void finalize_ws(const unsigned int* __restrict__ part, const float* __restrict__ hfac,
                 const float* __restrict__ W, float* __restrict__ out)
{
    __shared__ float2 red[512];
    const int s    = threadIdx.x & 63;        // slot within block's 64
    const int kq   = threadIdx.x >> 6;        // 0..7
    const int slot = blockIdx.x * 64 + s;     // 0..8191
    float sx = 0.f, sy = 0.f;
    #pragma unroll 8
    for (int k = kq * 64; k < kq * 64 + 64; ++k) {
        const unsigned int v = part[(size_t)k * SLOTS + slot];
        const f16x2 h = __builtin_bit_cast(f16x2, v);
        sx += (float)h[0];
        sy += (float)h[1];
    }
    red[threadIdx.x] = make_float2(sx, sy);
    __syncthreads();
    if (threadIdx.x < 64) {
        float tx = red[s].x, ty = red[s].y;
        #pragma unroll
        for (int g = 1; g < 8; ++g) {
            const float2 v = red[g * 64 + s];
            tx += v.x; ty += v.y;
        }
        // un-permute slot -> (p, q): slot = qh*4096 + wv*1024 + i*512 + qt*128 + rp*64 + lane
        const int lane = slot & 63;
        const int rp   = (slot >> 6) & 1;
        const int qt   = (slot >> 7) & 3;
        const int ii   = (slot >> 9) & 1;
        const int wv   = (slot >> 10) & 3;
        const int qhh  = slot >> 12;
        const int p    = wv * 32 + ii * 16 + ((lane >> 4) << 2) + rp * 2;
        const int q    = qhh * QH + qt * 16 + (lane & 15);
        const float scale = (float)((0.005 - 0.00525) / (double)(BB * TT));
        const float hf = hfac[q];
        out[p * NN + q]       = fmaf(tx, scale, hf * W[p * NN + q]);
        out[(p + 1) * NN + q] = fmaf(ty, scale, hf * W[(p + 1) * NN + q]);
    }
}

// fallback epilogue when S was atomically accumulated in d_out
__global__ void finalize_at(const float* __restrict__ hfac, const float* __restrict__ W,
                            float* __restrict__ out)
{
    const int i = (blockIdx.x * 256 + threadIdx.x) * 2;
    const int q = i & 127;
    const float scale = (float)((0.005 - 0.00525) / (double)(BB * TT));
    float2 s = *(const float2*)(out + i);
    float2 w = *(const float2*)(W + i);
    float2 o;
    o.x = fmaf(s.x, scale, hfac[q] * w.x);
    o.y = fmaf(s.y, scale, hfac[q + 1] * w.y);
    *(float2*)(out + i) = o;
}

extern "C" void kernel_launch(void* const* d_in, const int* in_sizes, int n_in,
                              void* d_out, int out_size, void* d_ws, size_t ws_size,
                              hipStream_t stream)
{
    const float* pre  = (const float*)d_in[0];
    const float* post = (const float*)d_in[1];
    const float* W    = (const float*)d_in[2];
    const int*   dtp  = (const int*)d_in[3];
    float* out = (float*)d_out;

    const size_t part_bytes  = (size_t)NCH * SLOTS * sizeof(unsigned int);  // 16 MiB
    const size_t wpost_bytes = (size_t)NN * NCH * sizeof(float);            // 256 KiB
    const size_t need = part_bytes + wpost_bytes + NN * sizeof(float);

    if (ws_size >= need) {
        unsigned int* part = (unsigned int*)d_ws;
        float* wpost       = (float*)((char*)d_ws + part_bytes);
        float* hfac        = (float*)((char*)d_ws + part_bytes + wpost_bytes);
        hipLaunchKernelGGL((stdp_main<false>), dim3(NBLK), dim3(256), 0, stream,
                           pre, post, dtp, part, wpost, (float*)nullptr);
        hipLaunchKernelGGL(hfac_kernel, dim3(NN), dim3(64), 0, stream, wpost, dtp, hfac, NCH);
        hipLaunchKernelGGL(finalize_ws, dim3(SLOTS / 64), dim3(512), 0, stream, part, hfac, W, out);
    } else {
        // atomic fallback: needs only ~1 KiB of workspace
        float* wpost = (float*)d_ws;
        float* hfac  = wpost + NN;
        hipMemsetAsync(d_out, 0, OUTN * sizeof(float), stream);
        hipMemsetAsync(wpost, 0, NN * sizeof(float), stream);
        hipLaunchKernelGGL((stdp_main<true>), dim3(NBLK), dim3(256), 0, stream,
                           pre, post, dtp, (unsigned int*)nullptr, wpost, out);
        hipLaunchKernelGGL(hfac_kernel, dim3(NN), dim3(64), 0, stream, wpost, dtp, hfac, 1);
        hipLaunchKernelGGL(finalize_at, dim3(OUTN / 512), dim3(256), 0, stream, hfac, W, out);
    }
}

// Round 10
// 165.924 us; speedup vs baseline: 2.3961x; 1.0299x over previous
//
#include <hip/hip_runtime.h>

#define BB 16
#define TT 8192
#define NN 128                     // N_PRE == N_POST
constexpr int CHUNK = 256;         // time-steps per block
constexpr int NBLK  = BB * TT / CHUNK;   // 512 blocks
constexpr int OUTN  = NN * NN;           // 16384
constexpr int GS    = 264;         // g_lds row stride in halves (528 B rows, 16B-aligned)
constexpr int SLOTS = OUTN / 2;    // 8192 packed u32 slots per k-slice
constexpr int PROWS = 315;         // staged post rows: (t0, t0+315]

typedef _Float16 f16x8 __attribute__((ext_vector_type(8)));
typedef _Float16 f16x2 __attribute__((ext_vector_type(2)));
typedef float    f32x4 __attribute__((ext_vector_type(4)));

__device__ __forceinline__ unsigned short h16(float x) {
    _Float16 h = (_Float16)x;
    return __builtin_bit_cast(unsigned short, h);
}
__device__ __forceinline__ unsigned int pack2(float x, float y) {
    return (unsigned int)h16(x) | ((unsigned int)h16(y) << 16);
}
__device__ __forceinline__ float2 ldL(const unsigned short* p_lds, int m, int q0) {
    const unsigned int v = *(const unsigned int*)&p_lds[m * NN + q0];
    const f16x2 h = __builtin_bit_cast(f16x2, v);
    return make_float2((float)h[0], (float)h[1]);
}

// grid 512 x 512 threads. Block = one 256-step chunk of one batch.  (r7-proven: 53.6 us)
// Phase 0: stage post rows (t0, t0+315] as f16 into LDS (float4-coalesced).
// Phase 1: wave wv filters 32-step window wv from LDS (2 q per lane) into regs.
// Phase 2: dump g over the post region; ps write; MFMA over K=256.
template<bool ATOMIC>
__global__ __launch_bounds__(512, 4)
void stdp_main(const float* __restrict__ pre, const float* __restrict__ post,
               const int* __restrict__ dtp,
               unsigned int* __restrict__ part, float* __restrict__ wpost,
               float* __restrict__ outat)
{
    __shared__ __align__(16) char smem[PROWS * NN * 2];      // 80,640 B
    unsigned short* post_lds = (unsigned short*)smem;        // [315][128] f16
    unsigned short* g_lds    = (unsigned short*)smem;        // [128][264] f16 (phase 2)
    float*          lds_ps   = (float*)(smem + NN * GS * 2); // [8][128] (phase 2)

    const int tid   = threadIdx.x;
    const int blk   = blockIdx.x;
    const int b     = blk >> 5;          // 16 batches
    const int chunk = blk & 31;          // 32 chunks per batch
    const int t0    = chunk * CHUNK;
    const int wv    = tid >> 6;          // wave 0..7
    const int lane  = tid & 63;

    const float dtf = (float)(*dtp);
    const float r   = expf(-dtf * (1.0f / 20.0f));

    const float* pb = post + (size_t)b * TT * NN;
    const float* ab = pre  + (size_t)b * TT * NN;

    // ---------- phase 0: stage post tile ----------
    {
        const int c  = tid & 31;         // float4 column within row
        const int mr = tid >> 5;         // starting row
        for (int m = mr; m < PROWS; m += 16) {
            const int t = t0 + 1 + m;
            float4 v = make_float4(0.f, 0.f, 0.f, 0.f);
            if (t < TT) v = *(const float4*)(pb + (size_t)t * NN + c * 4);
            *(uint2*)&post_lds[m * NN + c * 4] = make_uint2(pack2(v.x, v.y), pack2(v.z, v.w));
        }
    }
    __syncthreads();

    // ---------- phase 1: filter window wv (32 steps), 2 q per lane ----------
    const int win  = wv;
    const int q0   = lane * 2;
    const int base = win * 32;           // local row base: P[ts+k] -> row base+k-1
    float ps0 = 0.f, ps1 = 0.f;          // post sums over (ts, ts+32]

    unsigned int pk0[16], pk1[16];       // 32 f16 steps per q
    {
        float2 p  = ldL(post_lds, base + 31, q0);   // tau=1: P[ts+32]
        float wt  = r;
        float gx = r * p.x, gy = r * p.y;
        ps0 += p.x; ps1 += p.y;
        #pragma unroll
        for (int tau = 2; tau <= 59; ++tau) {
            wt *= r;
            p = ldL(post_lds, base + 30 + tau, q0);
            gx = fmaf(wt, p.x, gx);
            gy = fmaf(wt, p.y, gy);
        }
        const float r60 = wt * r;        // r^60, consistent with chained weights
        pk0[15] = (unsigned int)h16(gx) << 16;   // step 31 = high half of word 15
        pk1[15] = (unsigned int)h16(gy) << 16;
        // recurrence downward: g[t] = r*(g[t+1]+P(t+1)) - r^60*P(t+60)
        #pragma unroll
        for (int c = 30; c >= 0; --c) {
            const float2 p1  = ldL(post_lds, base + c,      q0);  // P[ts+c+1]
            const float2 p60 = ldL(post_lds, base + c + 59, q0);  // P[ts+c+60]
            gx = r * (gx + p1.x) - r60 * p60.x;
            gy = r * (gy + p1.y) - r60 * p60.y;
            ps0 += p1.x; ps1 += p1.y;
            if (c & 1) {
                pk0[c >> 1] = (unsigned int)h16(gx) << 16;
                pk1[c >> 1] = (unsigned int)h16(gy) << 16;
            } else {
                pk0[c >> 1] |= h16(gx);
                pk1[c >> 1] |= h16(gy);
            }
        }
    }
    __syncthreads();                     // all post_lds reads done before overwrite

    // ---------- phase 2a: dump g over the post region; stash ps ----------
    {
        unsigned short* d0 = &g_lds[q0 * GS + win * 32];
        unsigned short* d1 = &g_lds[(q0 + 1) * GS + win * 32];
        #pragma unroll
        for (int s = 0; s < 4; ++s) {
            *(uint4*)(d0 + 8 * s) = make_uint4(pk0[4*s], pk0[4*s+1], pk0[4*s+2], pk0[4*s+3]);
            *(uint4*)(d1 + 8 * s) = make_uint4(pk1[4*s], pk1[4*s+1], pk1[4*s+2], pk1[4*s+3]);
        }
        lds_ps[win * NN + q0]     = ps0;
        lds_ps[win * NN + q0 + 1] = ps1;
    }
    __syncthreads();

    // ---------- post column sums (data valid as of the sync above) ----------
    if (tid < NN) {
        float s = 0.f;
        #pragma unroll
        for (int w = 0; w < 8; ++w) s += lds_ps[w * NN + tid];
        if (chunk == 0) s += pb[tid];    // window (t0,t0+256] misses t=0 row once per batch
        if constexpr (ATOMIC) atomicAdd(&wpost[tid], s);
        else wpost[(size_t)tid * NBLK + blk] = s;   // [q][NBLK] for coalesced reduce
    }

    // ---------- phase 2b: MFMA S[p,q] += pre^T @ g, K=256 ----------
    const int pr0 = wv * 16;
    f32x4 acc[8];
    #pragma unroll
    for (int qt = 0; qt < 8; ++qt) acc[qt] = (f32x4){0.f, 0.f, 0.f, 0.f};

    const float* abase = ab + (size_t)(t0 + (lane >> 4) * 8) * NN + pr0 + (lane & 15);
    float an[8];
    #pragma unroll
    for (int j = 0; j < 8; ++j) an[j] = abase[(size_t)j * NN];      // ks=0 raw f32

    #pragma unroll
    for (int ks = 0; ks < 8; ++ks) {
        f16x8 af;
        #pragma unroll
        for (int j = 0; j < 8; ++j) af[j] = (_Float16)an[j];        // 0/1 exact in fp16
        if (ks < 7) {
            const float* src = abase + (size_t)((ks + 1) * 32) * NN;
            #pragma unroll
            for (int j = 0; j < 8; ++j) an[j] = src[(size_t)j * NN]; // prefetch ks+1
        }
        const int koff = ks * 32 + (lane >> 4) * 8;
        #pragma unroll
        for (int qt = 0; qt < 8; ++qt) {
            const f16x8 bf = *(const f16x8*)&g_lds[(qt * 16 + (lane & 15)) * GS + koff];
            acc[qt] = __builtin_amdgcn_mfma_f32_16x16x32_f16(af, bf, acc[qt], 0, 0, 0);
        }
    }

    // ---------- write partial S: u32-packed f16 pairs, 256B/instr coalesced ----------
    if constexpr (!ATOMIC) {
        unsigned int* dst = part + ((size_t)blk * 8 + wv) * 1024 + lane;  // 8 qt * 2 rgpair * 64
        #pragma unroll
        for (int qt = 0; qt < 8; ++qt)
            #pragma unroll
            for (int rp = 0; rp < 2; ++rp)
                dst[qt * 128 + rp * 64] = pack2(acc[qt][2 * rp], acc[qt][2 * rp + 1]);
    } else {
        #pragma unroll
        for (int qt = 0; qt < 8; ++qt)
            #pragma unroll
            for (int rg = 0; rg < 4; ++rg) {
                const int prow = pr0 + (lane >> 4) * 4 + rg;
                const int qcol = qt * 16 + (lane & 15);
                atomicAdd(&outat[prow * NN + qcol], acc[qt][rg]);
            }
    }
}

// fused split-K reduce + hfac + epilogue: 128 blocks x 512 thr.
// Each block's 64 slots share a single qt => only 16 distinct q values:
// reduce wpost[q][0..511] in-kernel (coalesced), no separate hfac kernel.
__global__ __launch_bounds__(512)
void finalize_ws(const unsigned int* __restrict__ part, const float* __restrict__ wpost,
                 const int* __restrict__ dtp, const float* __restrict__ W,
                 float* __restrict__ out)
{
    __shared__ float2 red[512];
    __shared__ float  hfs[16];
    const int s    = threadIdx.x & 63;        // slot within block's 64
    const int kq   = threadIdx.x >> 6;        // 0..7
    const int slot = blockIdx.x * 64 + s;     // 0..8191
    const int qt   = (slot >> 7) & 7;         // fixed for whole block
    const int qbase = qt * 16;

    // hfac for this block's 16 q: 32 threads per q, 16 chunks each, shfl reduce
    {
        const int qi   = threadIdx.x >> 5;    // 0..15
        const int part5 = threadIdx.x & 31;
        float hsum = 0.f;
        const float* wq = wpost + (size_t)(qbase + qi) * NBLK;
        #pragma unroll
        for (int k = part5; k < NBLK; k += 32) hsum += wq[k];
        #pragma unroll
        for (int off = 16; off; off >>= 1) hsum += __shfl_down(hsum, off, 32);
        if (part5 == 0) {
            const float dtf   = (float)(*dtp);
            const float alpha = dtf * 1e-3f;
            hfs[qi] = -0.001f * (alpha * (hsum * (1.0f / (float)(BB * TT)) - 0.1f));
        }
    }

    float sx = 0.f, sy = 0.f;
    #pragma unroll 8
    for (int k = kq * 64; k < kq * 64 + 64; ++k) {
        const unsigned int v = part[(size_t)k * SLOTS + slot];
        const f16x2 h = __builtin_bit_cast(f16x2, v);
        sx += (float)h[0];
        sy += (float)h[1];
    }
    red[threadIdx.x] = make_float2(sx, sy);
    __syncthreads();
    if (threadIdx.x < 64) {
        float tx = red[s].x, ty = red[s].y;
        #pragma unroll
        for (int g = 1; g < 8; ++g) {
            const float2 v = red[g * 64 + s];
            tx += v.x; ty += v.y;
        }
        // un-permute slot -> (p, q)
        const int lane = slot & 63;
        const int rp   = (slot >> 6) & 1;
        const int wv   = slot >> 10;
        const int p    = wv * 16 + ((lane >> 4) << 2) + rp * 2;
        const int qi   = lane & 15;
        const int q    = qbase + qi;
        const float scale = (float)((0.005 - 0.00525) / (double)(BB * TT));
        const float hf = hfs[qi];
        out[p * NN + q]       = fmaf(tx, scale, hf * W[p * NN + q]);
        out[(p + 1) * NN + q] = fmaf(ty, scale, hf * W[(p + 1) * NN + q]);
    }
}

// fallback epilogue when S was atomically accumulated in d_out
__global__ void finalize_at(const float* __restrict__ wpost, const int* __restrict__ dtp,
                            const float* __restrict__ W, float* __restrict__ out)
{
    const int i = (blockIdx.x * 256 + threadIdx.x) * 2;
    const int q = i & 127;
    const float scale = (float)((0.005 - 0.00525) / (double)(BB * TT));
    const float dtf   = (float)(*dtp);
    const float alpha = dtf * 1e-3f;
    const float inv   = 1.0f / (float)(BB * TT);
    const float hf0   = -0.001f * (alpha * (wpost[q]     * inv - 0.1f));
    const float hf1   = -0.001f * (alpha * (wpost[q + 1] * inv - 0.1f));
    float2 sv = *(const float2*)(out + i);
    float2 w  = *(const float2*)(W + i);
    float2 o;
    o.x = fmaf(sv.x, scale, hf0 * w.x);
    o.y = fmaf(sv.y, scale, hf1 * w.y);
    *(float2*)(out + i) = o;
}

extern "C" void kernel_launch(void* const* d_in, const int* in_sizes, int n_in,
                              void* d_out, int out_size, void* d_ws, size_t ws_size,
                              hipStream_t stream)
{
    const float* pre  = (const float*)d_in[0];
    const float* post = (const float*)d_in[1];
    const float* W    = (const float*)d_in[2];
    const int*   dtp  = (const int*)d_in[3];
    float* out = (float*)d_out;

    const size_t part_bytes  = (size_t)NBLK * SLOTS * sizeof(unsigned int); // 16 MiB
    const size_t wpost_bytes = (size_t)NN * NBLK * sizeof(float);           // 256 KiB
    const size_t need = part_bytes + wpost_bytes;

    if (ws_size >= need) {
        unsigned int* part = (unsigned int*)d_ws;
        float* wpost       = (float*)((char*)d_ws + part_bytes);
        hipLaunchKernelGGL((stdp_main<false>), dim3(NBLK), dim3(512), 0, stream,
                           pre, post, dtp, part, wpost, (float*)nullptr);
        hipLaunchKernelGGL(finalize_ws, dim3(SLOTS / 64), dim3(512), 0, stream,
                           part, wpost, dtp, W, out);
    } else {
        // atomic fallback: needs only 512 B of workspace
        float* wpost = (float*)d_ws;
        hipMemsetAsync(d_out, 0, OUTN * sizeof(float), stream);
        hipMemsetAsync(wpost, 0, NN * sizeof(float), stream);
        hipLaunchKernelGGL((stdp_main<true>), dim3(NBLK), dim3(512), 0, stream,
                           pre, post, dtp, (unsigned int*)nullptr, wpost, out);
        hipLaunchKernelGGL(finalize_at, dim3(OUTN / 512), dim3(256), 0, stream,
                           wpost, dtp, W, out);
    }
}

// Round 11
// 158.338 us; speedup vs baseline: 2.5109x; 1.0479x over previous
//
#include <hip/hip_runtime.h>

#define BB 16
#define TT 8192
#define NN 128                     // N_PRE == N_POST
constexpr int CHUNK = 256;         // time-steps per chunk
constexpr int NCH   = BB * TT / CHUNK;   // 512 chunks
constexpr int NBLK  = NCH / 2;           // 256 blocks, 2 chunks each
constexpr int OUTN  = NN * NN;           // 16384
constexpr int GS    = 264;         // bufG row stride in halves (528 B, 16B-aligned)
constexpr int SLOTS = OUTN / 2;    // 8192 packed u32 slots per block-slice
constexpr int PROWS = 315;         // staged post rows per chunk: (t0, t0+315]

typedef _Float16 f16x8 __attribute__((ext_vector_type(8)));
typedef _Float16 f16x2 __attribute__((ext_vector_type(2)));
typedef float    f32x4 __attribute__((ext_vector_type(4)));

__device__ __forceinline__ unsigned short h16(float x) {
    _Float16 h = (_Float16)x;
    return __builtin_bit_cast(unsigned short, h);
}
__device__ __forceinline__ unsigned int pack2(float x, float y) {
    return (unsigned int)h16(x) | ((unsigned int)h16(y) << 16);
}
__device__ __forceinline__ float2 ldL(const unsigned short* p_lds, int m, int q0) {
    const unsigned int v = *(const unsigned int*)&p_lds[m * NN + q0];
    const f16x2 h = __builtin_bit_cast(f16x2, v);
    return make_float2((float)h[0], (float)h[1]);
}

// grid 256 x 512 threads, 1 block/CU (152 KB LDS). Block = chunks 2*bi, 2*bi+1.
// Pipeline: stage c0 -> issue c1 loads -> filter c0 (overlaps c1 drain) ->
// g0 dump -> barrier -> c1 regs->bufP -> MFMA c0 -> barrier -> filter c1 ->
// g1 dump -> barrier -> MFMA c1 (acc over both) -> single combined partial.
template<bool ATOMIC>
__global__ __launch_bounds__(512, 2)
void stdp_main(const float* __restrict__ pre, const float* __restrict__ post,
               const int* __restrict__ dtp,
               unsigned int* __restrict__ part, float* __restrict__ wpost,
               float* __restrict__ outat)
{
    __shared__ __align__(16) unsigned short bufP[PROWS * NN];   // 80,640 B post tile
    __shared__ __align__(16) unsigned short bufG[NN * GS];      // 67,584 B g tile
    __shared__ float lds_ps[8 * NN];                            // 4 KB

    const int tid    = threadIdx.x;
    const int bi     = blockIdx.x;
    const int c0g    = bi * 2;           // global chunk ids c0g, c0g+1 (same batch)
    const int b      = c0g >> 5;
    const int chunk0 = c0g & 31;         // even, 0..30
    const int t00    = chunk0 * CHUNK;
    const int t01    = t00 + CHUNK;
    const int wv     = tid >> 6;         // wave 0..7
    const int lane   = tid & 63;

    const float dtf = (float)(*dtp);
    const float r   = expf(-dtf * (1.0f / 20.0f));

    const float* pb = post + (size_t)b * TT * NN;
    const float* ab = pre  + (size_t)b * TT * NN;

    const int sc = tid & 31;             // staging: float4 column
    const int mr = tid >> 5;             // staging: starting row (0..15)

    // ---------- stage c0 post tile into bufP ----------
    for (int m = mr; m < PROWS; m += 16) {
        const int t = t00 + 1 + m;       // c0 even => t00+315 <= 7995 < TT, no guard needed
        const float4 v = *(const float4*)(pb + (size_t)t * NN + sc * 4);
        *(uint2*)&bufP[m * NN + sc * 4] = make_uint2(pack2(v.x, v.y), pack2(v.z, v.w));
    }
    __syncthreads();

    // ---------- issue c1 staging loads into registers (drain overlaps filter c0) ----------
    float4 va[20];
    #pragma unroll
    for (int i = 0; i < 20; ++i) {
        const int m = mr + i * 16;
        const int t = t01 + 1 + m;
        va[i] = make_float4(0.f, 0.f, 0.f, 0.f);
        if (m < PROWS && t < TT) va[i] = *(const float4*)(pb + (size_t)t * NN + sc * 4);
    }

    const int q0 = lane * 2;

    // ---------- filter c0: window wv (32 steps), 2 q per lane ----------
    unsigned int pk0[16], pk1[16];
    float ps0, ps1;
    #define FILTER_PHASE(SRC) {                                               \
        const int base = wv * 32;                                             \
        ps0 = 0.f; ps1 = 0.f;                                                 \
        float2 p  = ldL(SRC, base + 31, q0);                                  \
        float wt  = r;                                                        \
        float gx = r * p.x, gy = r * p.y;                                     \
        ps0 += p.x; ps1 += p.y;                                               \
        _Pragma("unroll")                                                     \
        for (int tau = 2; tau <= 59; ++tau) {                                 \
            wt *= r;                                                          \
            p = ldL(SRC, base + 30 + tau, q0);                                \
            gx = fmaf(wt, p.x, gx);                                           \
            gy = fmaf(wt, p.y, gy);                                           \
        }                                                                     \
        const float r60 = wt * r;                                             \
        pk0[15] = (unsigned int)h16(gx) << 16;                                \
        pk1[15] = (unsigned int)h16(gy) << 16;                                \
        _Pragma("unroll")                                                     \
        for (int c = 30; c >= 0; --c) {                                       \
            const float2 p1  = ldL(SRC, base + c,      q0);                   \
            const float2 p60 = ldL(SRC, base + c + 59, q0);                   \
            gx = r * (gx + p1.x) - r60 * p60.x;                               \
            gy = r * (gy + p1.y) - r60 * p60.y;                               \
            ps0 += p1.x; ps1 += p1.y;                                         \
            if (c & 1) {                                                      \
                pk0[c >> 1] = (unsigned int)h16(gx) << 16;                    \
                pk1[c >> 1] = (unsigned int)h16(gy) << 16;                    \
            } else {                                                          \
                pk0[c >> 1] |= h16(gx);                                       \
                pk1[c >> 1] |= h16(gy);                                       \
            }                                                                 \
        }                                                                     \
    }
    #define DUMP_G() {                                                        \
        unsigned short* d0 = &bufG[q0 * GS + wv * 32];                        \
        unsigned short* d1 = &bufG[(q0 + 1) * GS + wv * 32];                  \
        _Pragma("unroll")                                                     \
        for (int s = 0; s < 4; ++s) {                                         \
            *(uint4*)(d0 + 8*s) = make_uint4(pk0[4*s], pk0[4*s+1], pk0[4*s+2], pk0[4*s+3]); \
            *(uint4*)(d1 + 8*s) = make_uint4(pk1[4*s], pk1[4*s+1], pk1[4*s+2], pk1[4*s+3]); \
        }                                                                     \
        lds_ps[wv * NN + q0]     = ps0;                                       \
        lds_ps[wv * NN + q0 + 1] = ps1;                                       \
    }

    FILTER_PHASE(bufP)
    DUMP_G()
    __syncthreads();                     // bufP reads done; g0 + ps visible; c1 loads drained

    // ---------- store c1 post tile into bufP (safe: filter c0 complete) ----------
    #pragma unroll
    for (int i = 0; i < 20; ++i) {
        const int m = mr + i * 16;
        if (m < PROWS)
            *(uint2*)&bufP[m * NN + sc * 4] =
                make_uint2(pack2(va[i].x, va[i].y), pack2(va[i].z, va[i].w));
    }

    // ---------- wpost c0 ----------
    if (tid < NN) {
        float s = 0.f;
        #pragma unroll
        for (int w = 0; w < 8; ++w) s += lds_ps[w * NN + tid];
        if (chunk0 == 0) s += pb[tid];   // window (t0,t0+256] misses t=0 row once per batch
        if constexpr (ATOMIC) atomicAdd(&wpost[tid], s);
        else wpost[(size_t)tid * NCH + c0g] = s;
    }

    // ---------- MFMA c0 ----------
    const int pr0 = wv * 16;
    f32x4 acc[8];
    #pragma unroll
    for (int qt = 0; qt < 8; ++qt) acc[qt] = (f32x4){0.f, 0.f, 0.f, 0.f};

    #define MFMA_PHASE(T0) {                                                  \
        const float* abase = ab + (size_t)((T0) + (lane >> 4) * 8) * NN + pr0 + (lane & 15); \
        float an[8];                                                          \
        _Pragma("unroll")                                                     \
        for (int j = 0; j < 8; ++j) an[j] = abase[(size_t)j * NN];            \
        _Pragma("unroll")                                                     \
        for (int ks = 0; ks < 8; ++ks) {                                      \
            f16x8 af;                                                         \
            _Pragma("unroll")                                                 \
            for (int j = 0; j < 8; ++j) af[j] = (_Float16)an[j];              \
            if (ks < 7) {                                                     \
                const float* src = abase + (size_t)((ks + 1) * 32) * NN;      \
                _Pragma("unroll")                                             \
                for (int j = 0; j < 8; ++j) an[j] = src[(size_t)j * NN];      \
            }                                                                 \
            const int koff = ks * 32 + (lane >> 4) * 8;                       \
            _Pragma("unroll")                                                 \
            for (int qt = 0; qt < 8; ++qt) {                                  \
                const f16x8 bf = *(const f16x8*)&bufG[(qt * 16 + (lane & 15)) * GS + koff]; \
                acc[qt] = __builtin_amdgcn_mfma_f32_16x16x32_f16(af, bf, acc[qt], 0, 0, 0); \
            }                                                                 \
        }                                                                     \
    }

    MFMA_PHASE(t00)
    __syncthreads();                     // bufG reads done; bufP(c1) stores visible

    // ---------- filter c1 + dump g1 ----------
    FILTER_PHASE(bufP)
    DUMP_G()
    __syncthreads();

    // ---------- wpost c1 ----------
    if (tid < NN) {
        float s = 0.f;
        #pragma unroll
        for (int w = 0; w < 8; ++w) s += lds_ps[w * NN + tid];
        if constexpr (ATOMIC) atomicAdd(&wpost[tid], s);
        else wpost[(size_t)tid * NCH + c0g + 1] = s;
    }

    // ---------- MFMA c1 (accumulates onto acc) ----------
    MFMA_PHASE(t01)

    // ---------- write combined partial: u32-packed f16 pairs, coalesced ----------
    if constexpr (!ATOMIC) {
        unsigned int* dst = part + ((size_t)bi * 8 + wv) * 1024 + lane;
        #pragma unroll
        for (int qt = 0; qt < 8; ++qt)
            #pragma unroll
            for (int rp = 0; rp < 2; ++rp)
                dst[qt * 128 + rp * 64] = pack2(acc[qt][2 * rp], acc[qt][2 * rp + 1]);
    } else {
        #pragma unroll
        for (int qt = 0; qt < 8; ++qt)
            #pragma unroll
            for (int rg = 0; rg < 4; ++rg) {
                const int prow = pr0 + (lane >> 4) * 4 + rg;
                const int qcol = qt * 16 + (lane & 15);
                atomicAdd(&outat[prow * NN + qcol], acc[qt][rg]);
            }
    }
    #undef FILTER_PHASE
    #undef DUMP_G
    #undef MFMA_PHASE
}

// fused split-K reduce + hfac + epilogue: 128 blocks x 512 thr.
// Each block's 64 slots share one qt => 16 distinct q: hfac computed in-kernel.
__global__ __launch_bounds__(512)
void finalize_ws(const unsigned int* __restrict__ part, const float* __restrict__ wpost,
                 const int* __restrict__ dtp, const float* __restrict__ W,
                 float* __restrict__ out)
{
    __shared__ float2 red[512];
    __shared__ float  hfs[16];
    const int s    = threadIdx.x & 63;        // slot within block's 64
    const int kq   = threadIdx.x >> 6;        // 0..7
    const int slot = blockIdx.x * 64 + s;     // 0..8191
    const int qt   = (slot >> 7) & 7;         // fixed for whole block
    const int qbase = qt * 16;

    // hfac: 32 threads per q, shfl reduce over wpost[q][0..NCH)
    {
        const int qi = threadIdx.x >> 5;      // 0..15
        const int pr = threadIdx.x & 31;
        float hsum = 0.f;
        const float* wq = wpost + (size_t)(qbase + qi) * NCH;
        #pragma unroll 4
        for (int k = pr; k < NCH; k += 32) hsum += wq[k];
        #pragma unroll
        for (int off = 16; off; off >>= 1) hsum += __shfl_down(hsum, off, 32);
        if (pr == 0) {
            const float dtf   = (float)(*dtp);
            const float alpha = dtf * 1e-3f;
            hfs[qi] = -0.001f * (alpha * (hsum * (1.0f / (float)(BB * TT)) - 0.1f));
        }
    }

    float sx = 0.f, sy = 0.f;
    #pragma unroll 8
    for (int k = kq * (NBLK / 8); k < (kq + 1) * (NBLK / 8); ++k) {
        const unsigned int v = part[(size_t)k * SLOTS + slot];
        const f16x2 h = __builtin_bit_cast(f16x2, v);
        sx += (float)h[0];
        sy += (float)h[1];
    }
    red[threadIdx.x] = make_float2(sx, sy);
    __syncthreads();
    if (threadIdx.x < 64) {
        float tx = red[s].x, ty = red[s].y;
        #pragma unroll
        for (int g = 1; g < 8; ++g) {
            const float2 v = red[g * 64 + s];
            tx += v.x; ty += v.y;
        }
        // un-permute slot -> (p, q)
        const int lane = slot & 63;
        const int rp   = (slot >> 6) & 1;
        const int wv   = slot >> 10;
        const int p    = wv * 16 + ((lane >> 4) << 2) + rp * 2;
        const int qi   = lane & 15;
        const int q    = qbase + qi;
        const float scale = (float)((0.005 - 0.00525) / (double)(BB * TT));
        const float hf = hfs[qi];
        out[p * NN + q]       = fmaf(tx, scale, hf * W[p * NN + q]);
        out[(p + 1) * NN + q] = fmaf(ty, scale, hf * W[(p + 1) * NN + q]);
    }
}

// fallback epilogue when S was atomically accumulated in d_out
__global__ void finalize_at(const float* __restrict__ wpost, const int* __restrict__ dtp,
                            const float* __restrict__ W, float* __restrict__ out)
{
    const int i = (blockIdx.x * 256 + threadIdx.x) * 2;
    const int q = i & 127;
    const float scale = (float)((0.005 - 0.00525) / (double)(BB * TT));
    const float dtf   = (float)(*dtp);
    const float alpha = dtf * 1e-3f;
    const float inv   = 1.0f / (float)(BB * TT);
    const float hf0   = -0.001f * (alpha * (wpost[q]     * inv - 0.1f));
    const float hf1   = -0.001f * (alpha * (wpost[q + 1] * inv - 0.1f));
    float2 sv = *(const float2*)(out + i);
    float2 w  = *(const float2*)(W + i);
    float2 o;
    o.x = fmaf(sv.x, scale, hf0 * w.x);
    o.y = fmaf(sv.y, scale, hf1 * w.y);
    *(float2*)(out + i) = o;
}

extern "C" void kernel_launch(void* const* d_in, const int* in_sizes, int n_in,
                              void* d_out, int out_size, void* d_ws, size_t ws_size,
                              hipStream_t stream)
{
    const float* pre  = (const float*)d_in[0];
    const float* post = (const float*)d_in[1];
    const float* W    = (const float*)d_in[2];
    const int*   dtp  = (const int*)d_in[3];
    float* out = (float*)d_out;

    const size_t part_bytes  = (size_t)NBLK * SLOTS * sizeof(unsigned int); // 8 MiB
    const size_t wpost_bytes = (size_t)NN * NCH * sizeof(float);            // 256 KiB
    const size_t need = part_bytes + wpost_bytes;

    if (ws_size >= need) {
        unsigned int* part = (unsigned int*)d_ws;
        float* wpost       = (float*)((char*)d_ws + part_bytes);
        hipLaunchKernelGGL((stdp_main<false>), dim3(NBLK), dim3(512), 0, stream,
                           pre, post, dtp, part, wpost, (float*)nullptr);
        hipLaunchKernelGGL(finalize_ws, dim3(SLOTS / 64), dim3(512), 0, stream,
                           part, wpost, dtp, W, out);
    } else {
        // atomic fallback: needs only 512 B of workspace
        float* wpost = (float*)d_ws;
        hipMemsetAsync(d_out, 0, OUTN * sizeof(float), stream);
        hipMemsetAsync(wpost, 0, NN * sizeof(float), stream);
        hipLaunchKernelGGL((stdp_main<true>), dim3(NBLK), dim3(512), 0, stream,
                           pre, post, dtp, (unsigned int*)nullptr, wpost, out);
        hipLaunchKernelGGL(finalize_at, dim3(OUTN / 512), dim3(256), 0, stream,
                           wpost, dtp, W, out);
    }
}